// Round 5
// baseline (117.184 us; speedup 1.0000x reference)
//
#include <hip/hip_runtime.h>

// Fused iterated 3x3 median blur (edge-replicate), up to 9 iterations.
//
// R5 = R4 resubmitted (R4 bench was an infra failure: container died twice
// before compile/test; no counters produced).
//
// R4: wave-autonomous tiles (validated in R3) with the per-lane patch cut
// 7x7 -> 6x6 so the register state FITS (R3's VGPR_Count=68 proved
// stage[49] spilled to scratch -> ~50 scratch ops/iter dominated).
// One wave (64 threads) per block owns a 32x32 output tile + 9 halo =
// 50x50 LDS (10 KB -> 16 blocks/CU = 16 waves/CU, 4/SIMD). Each lane owns
// a 6x6 patch of compute region [1,48]^2 in registers (stage[36], in-place
// update); per iteration only the 28-cell halo ring is read from LDS and
// the 20-cell patch perimeter written back. All exchange intra-wave ->
// both per-iteration barriers are single-wave (near-free).
// Validity: state-k valid on [k,49-k]^2, k<=9 -> [9,40]^2 = output tile.
// Image-edge replicate pads are register fixups in pad-owning lanes (row
// fix then col fix -> corners exact); perimeter writes publish them.
// Grid: 16x16 tiles of 32 (exact) x 32 batches.

#define TD 50
#define OW 32
#define P  6
#define RAD 9
#define NT 64

__device__ __forceinline__ float min3f(float a, float b, float c) { return fminf(fminf(a, b), c); }
__device__ __forceinline__ float max3f(float a, float b, float c) { return fmaxf(fmaxf(a, b), c); }
__device__ __forceinline__ float med3f(float a, float b, float c) { return __builtin_amdgcn_fmed3f(a, b, c); }

__global__ __launch_bounds__(NT, 4) void median_fused_kernel(
    const float* __restrict__ src, float* __restrict__ dst,
    const int* __restrict__ t)
{
    __shared__ float buf[TD * TD];

    const int b   = blockIdx.y;
    const int ty  = blockIdx.x >> 4;
    const int tx  = blockIdx.x & 15;
    const int y0  = ty * OW;
    const int x0  = tx * OW;
    const int tid = threadIdx.x;
    const float* img  = src + (b << 18);
    float*       outb = dst + (b << 18);

    int T = t[b];
    T = min(max(T, 0), 9);

    if (T == 0) {                       // straight vector copy, no LDS
        for (int idx = tid; idx < 256; idx += NT) {   // 32 rows x 8 float4
            int row = idx >> 3, c4 = idx & 7;
            *(float4*)&outb[((y0 + row) << 9) + x0 + (c4 << 2)] =
                *(const float4*)&img[((y0 + row) << 9) + x0 + (c4 << 2)];
        }
        return;
    }

    // ---- load 50x50 halo tile, clamped (= replicate-padded image) ----
    for (int i = tid; i < TD * TD; i += NT) {
        int r = i / TD, c = i - r * TD;
        int gy = min(max(y0 - RAD + r, 0), 511);
        int gx = min(max(x0 - RAD + c, 0), 511);
        buf[i] = img[(gy << 9) + gx];
    }

    // lane -> 6x6 patch of compute region [1,48]^2
    const int ptx = tid & 7;            // 8 col groups x 6
    const int pty = tid >> 3;           // 8 row groups x 6
    const int ub  = 1 + P * pty;        // patch rows [ub, ub+5]
    const int vb  = 1 + P * ptx;        // patch cols [vb, vb+5]

    // pad-owning lanes (tile row r <-> image row y0-9+r):
    //  y0==0  : image row 0 = r=9 (pty=1, i=2); pad r=8 -> i=1 <- i=2
    //  y0==480: image row 511 = r=40 (pty=6, i=3); pad r=41 -> i=4 <- i=3
    //  cols symmetric with ptx / x0.
    const bool padTop = (y0 == 0)   && (pty == 1);
    const bool padBot = (y0 == 480) && (pty == 6);
    const bool padLft = (x0 == 0)   && (ptx == 1);
    const bool padRgt = (x0 == 480) && (ptx == 6);

    __syncthreads();                    // single-wave: near-free

    // preload own 6x6 patch (state 0) into registers
    float stage[36];
    #pragma unroll
    for (int i = 0; i < 6; ++i)
        #pragma unroll
        for (int j = 0; j < 6; ++j)
            stage[i * 6 + j] = buf[(ub + i) * TD + vb + j];

    for (int k = 0; k < T; ++k) {
        float A[8], Br[8], C[8];
        // window row ub-1: all 8 from LDS (neighbor ring / static boundary)
        {
            const float* p = &buf[(ub - 1) * TD + (vb - 1)];
            #pragma unroll
            for (int j = 0; j < 8; ++j) A[j] = p[j];
        }
        // window row ub: edges from LDS, middle from stage row 0
        Br[0] = buf[ub * TD + (vb - 1)];
        #pragma unroll
        for (int j = 0; j < 6; ++j) Br[1 + j] = stage[j];
        Br[7] = buf[ub * TD + (vb + 6)];

        #pragma unroll
        for (int i = 0; i < 6; ++i) {
            if (i < 5) {                // rows ub+1..ub+5: edges LDS, mid regs
                C[0] = buf[(ub + 1 + i) * TD + (vb - 1)];
                #pragma unroll
                for (int j = 0; j < 6; ++j) C[1 + j] = stage[(i + 1) * 6 + j];
                C[7] = buf[(ub + 1 + i) * TD + (vb + 6)];
            } else {                    // row ub+6: all 8 from LDS
                const float* p = &buf[(ub + 6) * TD + (vb - 1)];
                #pragma unroll
                for (int j = 0; j < 8; ++j) C[j] = p[j];
            }
            float lo[8], mi[8], hi[8];
            #pragma unroll
            for (int j = 0; j < 8; ++j) {
                lo[j] = min3f(A[j], Br[j], C[j]);
                mi[j] = med3f(A[j], Br[j], C[j]);
                hi[j] = max3f(A[j], Br[j], C[j]);
            }
            // in-place: old row i is in Br; row i+1 already consumed into C
            #pragma unroll
            for (int j = 0; j < 6; ++j)
                stage[i * 6 + j] = med3f(max3f(lo[j], lo[j+1], lo[j+2]),
                                         med3f(mi[j], mi[j+1], mi[j+2]),
                                         min3f(hi[j], hi[j+1], hi[j+2]));
            #pragma unroll
            for (int j = 0; j < 8; ++j) { A[j] = Br[j]; Br[j] = C[j]; }
        }

        // register pad fixups (row fix first, then col fix -> corners exact)
        if (padTop) {                   // row i=1 (r=8) <- row i=2 (r=9)
            #pragma unroll
            for (int j = 0; j < 6; ++j) stage[6 + j] = stage[12 + j];
        }
        if (padBot) {                   // row i=4 (r=41) <- row i=3 (r=40)
            #pragma unroll
            for (int j = 0; j < 6; ++j) stage[24 + j] = stage[18 + j];
        }
        if (padLft) {                   // col j=1 (c=8) <- col j=2 (c=9)
            #pragma unroll
            for (int i = 0; i < 6; ++i) stage[i * 6 + 1] = stage[i * 6 + 2];
        }
        if (padRgt) {                   // col j=4 (c=41) <- col j=3 (c=40)
            #pragma unroll
            for (int i = 0; i < 6; ++i) stage[i * 6 + 4] = stage[i * 6 + 3];
        }

        __syncthreads();                // all ring reads of state k done (WAR)

        if (k == T - 1) {               // final: write all 36 for store phase
            #pragma unroll
            for (int i = 0; i < 6; ++i)
                #pragma unroll
                for (int j = 0; j < 6; ++j)
                    buf[(ub + i) * TD + vb + j] = stage[i * 6 + j];
        } else {                        // write the 20-cell patch perimeter
            #pragma unroll
            for (int j = 0; j < 6; ++j) {
                buf[ub * TD + vb + j]       = stage[j];
                buf[(ub + 5) * TD + vb + j] = stage[30 + j];
            }
            #pragma unroll
            for (int i = 1; i < 5; ++i) {
                buf[(ub + i) * TD + vb]     = stage[i * 6];
                buf[(ub + i) * TD + vb + 5] = stage[i * 6 + 5];
            }
        }

        __syncthreads();                // new ring visible (RAW)
    }

    // ---- store 32x32 output tile, float4 global stores ----
    for (int idx = tid; idx < 256; idx += NT) {       // 32 rows x 8 float4
        int row = idx >> 3, c4 = idx & 7;
        const float* s = &buf[(RAD + row) * TD + RAD + (c4 << 2)];
        float4 v = { s[0], s[1], s[2], s[3] };
        *(float4*)&outb[((y0 + row) << 9) + x0 + (c4 << 2)] = v;
    }
}

extern "C" void kernel_launch(void* const* d_in, const int* in_sizes, int n_in,
                              void* d_out, int out_size, void* d_ws, size_t ws_size,
                              hipStream_t stream) {
    const float* x   = (const float*)d_in[0];
    const int*   t   = (const int*)d_in[1];
    float*       out = (float*)d_out;

    dim3 block(NT);
    dim3 grid(256, 32);   // 16x16 tiles of 32 x 32 batches
    median_fused_kernel<<<grid, block, 0, stream>>>(x, out, t);
}

// Round 6
// 113.993 us; speedup vs baseline: 1.0280x; 1.0280x over previous
//
#include <hip/hip_runtime.h>

// Fused iterated 3x3 median blur (edge-replicate), up to 9 iterations.
//
// R6: attacks R5's two measured walls:
//  (a) VGPR_Count=56 proved stage[36] STILL spilled under the runtime
//      k-loop -> T is now a compile-time template param (switch 1..9),
//      fully unrolling the k-loop into straight-line SSA.
//  (b) 8.23M LDS bank-conflict cycles (28% of runtime) + 48 scalar LDS
//      ops/iter: lane bank = (12*pty+6*ptx) mod 32 hit only 16 banks ->
//      structural 4-way. New stride TD=54 (54*6=324=4 mod 32) gives the
//      uniform 4-per-even-bank spread = MINIMUM bank-cycles for 8B ops;
//      full window rows are 4x float2 (ds_read_b64), side cells are
//      same-base scalar pairs (DS combiner -> ds_read2/write2):
//      ~24 LDS instrs/iter instead of 48.
//
// Structure (validated R3/R5): one wave per block owns a 32x32 output
// tile; compute region [1,48]^2 + static state-0 ring rows/cols 0,49 in
// LDS (50 rows x 54 stride = 10.8 KB -> 14 blocks/CU). Each lane owns a
// 6x6 patch in registers; per iteration reads the 28-cell halo ring from
// LDS, writes its 20-cell perimeter back. Validity: state-k valid at
// depth >= k -> after 9 iters [9,40]^2 = the output tile. Image-edge
// replicate pads are register fixups in pad-owning lanes (row fix then
// col fix -> corners exact); perimeter writes publish them.

#define TD   54
#define ROWS 50
#define OW   32
#define RAD  9
#define NT   64

static __device__ __forceinline__ float min3f(float a, float b, float c) { return fminf(fminf(a, b), c); }
static __device__ __forceinline__ float max3f(float a, float b, float c) { return fmaxf(fmaxf(a, b), c); }
static __device__ __forceinline__ float med3f(float a, float b, float c) { return __builtin_amdgcn_fmed3f(a, b, c); }

template<int T>
static __device__ __forceinline__ void run_iters(
    float* __restrict__ buf, int ub, int vb,
    bool padTop, bool padBot, bool padLft, bool padRgt)
{
    // preload own 6x6 patch (state 0) into registers
    float stage[36];
    #pragma unroll
    for (int i = 0; i < 6; ++i)
        #pragma unroll
        for (int j = 0; j < 6; ++j)
            stage[i * 6 + j] = buf[(ub + i) * TD + vb + j];

    #pragma unroll
    for (int k = 0; k < T; ++k) {
        float A[8], Br[8], C[8];
        // window row ub-1: 8 dwords from even base (vb-1 = 6*ptx) -> 4x b64
        {
            const float* p = &buf[(ub - 1) * TD + (vb - 1)];
            #pragma unroll
            for (int h = 0; h < 4; ++h) {
                float2 v = *(const float2*)(p + 2 * h);
                A[2 * h] = v.x; A[2 * h + 1] = v.y;
            }
        }
        // window row ub: side pair from LDS (same base, offsets 0 & 7),
        // middle from stage row 0
        {
            const float* p = &buf[ub * TD + (vb - 1)];
            Br[0] = p[0];
            Br[7] = p[7];
        }
        #pragma unroll
        for (int j = 0; j < 6; ++j) Br[1 + j] = stage[j];

        #pragma unroll
        for (int i = 0; i < 6; ++i) {
            if (i < 5) {                // rows ub+1..ub+5: side pair + regs
                const float* p = &buf[(ub + 1 + i) * TD + (vb - 1)];
                C[0] = p[0];
                C[7] = p[7];
                #pragma unroll
                for (int j = 0; j < 6; ++j) C[1 + j] = stage[(i + 1) * 6 + j];
            } else {                    // row ub+6: full row, 4x b64
                const float* p = &buf[(ub + 6) * TD + (vb - 1)];
                #pragma unroll
                for (int h = 0; h < 4; ++h) {
                    float2 v = *(const float2*)(p + 2 * h);
                    C[2 * h] = v.x; C[2 * h + 1] = v.y;
                }
            }
            float lo[8], mi[8], hi[8];
            #pragma unroll
            for (int j = 0; j < 8; ++j) {
                lo[j] = min3f(A[j], Br[j], C[j]);
                mi[j] = med3f(A[j], Br[j], C[j]);
                hi[j] = max3f(A[j], Br[j], C[j]);
            }
            // in-place: old row i is in Br; row i+1 already consumed into C
            #pragma unroll
            for (int j = 0; j < 6; ++j)
                stage[i * 6 + j] = med3f(max3f(lo[j], lo[j+1], lo[j+2]),
                                         med3f(mi[j], mi[j+1], mi[j+2]),
                                         min3f(hi[j], hi[j+1], hi[j+2]));
            #pragma unroll
            for (int j = 0; j < 8; ++j) { A[j] = Br[j]; Br[j] = C[j]; }
        }

        // register pad fixups (row fix first, then col fix -> corners exact)
        if (padTop) {                   // row i=1 (r=8) <- row i=2 (r=9)
            #pragma unroll
            for (int j = 0; j < 6; ++j) stage[6 + j] = stage[12 + j];
        }
        if (padBot) {                   // row i=4 (r=41) <- row i=3 (r=40)
            #pragma unroll
            for (int j = 0; j < 6; ++j) stage[24 + j] = stage[18 + j];
        }
        if (padLft) {                   // col j=1 (c=8) <- col j=2 (c=9)
            #pragma unroll
            for (int i = 0; i < 6; ++i) stage[i * 6 + 1] = stage[i * 6 + 2];
        }
        if (padRgt) {                   // col j=4 (c=41) <- col j=3 (c=40)
            #pragma unroll
            for (int i = 0; i < 6; ++i) stage[i * 6 + 4] = stage[i * 6 + 3];
        }

        __syncthreads();                // all ring reads of state k done (WAR)

        if (k == T - 1) {               // static: write all 36 for store phase
            #pragma unroll
            for (int i = 0; i < 6; ++i)
                #pragma unroll
                for (int j = 0; j < 6; ++j)
                    buf[(ub + i) * TD + vb + j] = stage[i * 6 + j];
        } else {                        // 20-cell perimeter (pairs -> write2)
            #pragma unroll
            for (int j = 0; j < 6; ++j) buf[ub * TD + vb + j]       = stage[j];
            #pragma unroll
            for (int j = 0; j < 6; ++j) buf[(ub + 5) * TD + vb + j] = stage[30 + j];
            #pragma unroll
            for (int i = 1; i < 5; ++i) {
                float* p = &buf[(ub + i) * TD + vb];
                p[0] = stage[i * 6];
                p[5] = stage[i * 6 + 5];
            }
        }

        __syncthreads();                // new ring visible (RAW)
    }
}

__global__ __launch_bounds__(NT, 3) void median_fused_kernel(
    const float* __restrict__ src, float* __restrict__ dst,
    const int* __restrict__ t)
{
    __shared__ float buf[ROWS * TD];

    const int b   = blockIdx.y;
    const int ty  = blockIdx.x >> 4;
    const int tx  = blockIdx.x & 15;
    const int y0  = ty * OW;
    const int x0  = tx * OW;
    const int tid = threadIdx.x;
    const float* img  = src + (b << 18);
    float*       outb = dst + (b << 18);

    int T = t[b];
    T = min(max(T, 0), 9);

    if (T == 0) {                       // straight vector copy, no LDS
        for (int idx = tid; idx < 256; idx += NT) {   // 32 rows x 8 float4
            int row = idx >> 3, c4 = idx & 7;
            *(float4*)&outb[((y0 + row) << 9) + x0 + (c4 << 2)] =
                *(const float4*)&img[((y0 + row) << 9) + x0 + (c4 << 2)];
        }
        return;
    }

    // ---- load 50x50 halo tile (stride 54), clamped (= replicate pad) ----
    for (int i = tid; i < ROWS * TD; i += NT) {
        int r = i / TD, c = i - r * TD;   // cols 50..53 = dead padding
        int gy = min(max(y0 - RAD + r, 0), 511);
        int gx = min(max(x0 - RAD + c, 0), 511);
        buf[i] = img[(gy << 9) + gx];
    }

    // lane -> 6x6 patch of compute region [1,48]^2
    const int ptx = tid & 7;            // 8 col groups x 6
    const int pty = tid >> 3;           // 8 row groups x 6
    const int ub  = 1 + 6 * pty;        // patch rows [ub, ub+5]
    const int vb  = 1 + 6 * ptx;        // patch cols [vb, vb+5]

    // pad-owning lanes (tile row r <-> image row y0-9+r):
    //  y0==0  : image row 0 = r=9 (pty=1,i=2); pad r=8 -> i=1 <- i=2
    //  y0==480: image row 511 = r=40 (pty=6,i=3); pad r=41 -> i=4 <- i=3
    const bool padTop = (y0 == 0)   && (pty == 1);
    const bool padBot = (y0 == 480) && (pty == 6);
    const bool padLft = (x0 == 0)   && (ptx == 1);
    const bool padRgt = (x0 == 480) && (ptx == 6);

    __syncthreads();

    switch (T) {
        case 1: run_iters<1>(buf, ub, vb, padTop, padBot, padLft, padRgt); break;
        case 2: run_iters<2>(buf, ub, vb, padTop, padBot, padLft, padRgt); break;
        case 3: run_iters<3>(buf, ub, vb, padTop, padBot, padLft, padRgt); break;
        case 4: run_iters<4>(buf, ub, vb, padTop, padBot, padLft, padRgt); break;
        case 5: run_iters<5>(buf, ub, vb, padTop, padBot, padLft, padRgt); break;
        case 6: run_iters<6>(buf, ub, vb, padTop, padBot, padLft, padRgt); break;
        case 7: run_iters<7>(buf, ub, vb, padTop, padBot, padLft, padRgt); break;
        case 8: run_iters<8>(buf, ub, vb, padTop, padBot, padLft, padRgt); break;
        default: run_iters<9>(buf, ub, vb, padTop, padBot, padLft, padRgt); break;
    }

    // ---- store 32x32 output tile, float4 global stores ----
    for (int idx = tid; idx < 256; idx += NT) {       // 32 rows x 8 float4
        int row = idx >> 3, c4 = idx & 7;
        const float* s = &buf[(RAD + row) * TD + RAD + (c4 << 2)];
        float4 v = { s[0], s[1], s[2], s[3] };
        *(float4*)&outb[((y0 + row) << 9) + x0 + (c4 << 2)] = v;
    }
}

extern "C" void kernel_launch(void* const* d_in, const int* in_sizes, int n_in,
                              void* d_out, int out_size, void* d_ws, size_t ws_size,
                              hipStream_t stream) {
    const float* x   = (const float*)d_in[0];
    const int*   t   = (const int*)d_in[1];
    float*       out = (float*)d_out;

    dim3 block(NT);
    dim3 grid(256, 32);   // 16x16 tiles of 32 x 32 batches
    median_fused_kernel<<<grid, block, 0, stream>>>(x, out, t);
}